// Round 5
// baseline (243.538 us; speedup 1.0000x reference)
//
#include <hip/hip_runtime.h>
#include <hip/hip_bf16.h>
#include <math.h>

// K[c,h,l] = sum_n W[c,h,n] * cos(Lambda[n]*l)
// GEMM (512 x 4096) x (4096 x 8192). Producer/consumer wave specialization:
//   waves 0-3 generate S-tiles in LDS (Chebyshev chains over l),
//   waves 4-7 do MFMA with A read global->reg (f32 W, L2-resident) + cvt.
// One barrier per K-step; producers fill buf^1 while consumers eat buf.

typedef __bf16 bf16_t;
typedef bf16_t bf16x8 __attribute__((ext_vector_type(8)));
typedef float f32x16 __attribute__((ext_vector_type(16)));

#define NK 4096
#define MH 512
#define LO 8192
#define BM 128
#define BN 128
#define BK 64
#define LDK 72   // Sl row stride (bf16): 144B = odd 16B multiple -> conflict-free b128

__device__ __forceinline__ uint32_t cvt_pk(float lo, float hi) {
    uint32_t r;
    asm("v_cvt_pk_bf16_f32 %0, %1, %2" : "=v"(r) : "v"(lo), "v"(hi));
    return r;
}

__global__ __launch_bounds__(512, 2) void dlr_pc(
    const float* __restrict__ W,
    const float* __restrict__ Lam,
    float* __restrict__ out)
{
    __shared__ uint32_t tbl[NK];            // 16 KB: (a<<16)|(e&0xffff), mu = a/2^13 + e*2^-29
    __shared__ float    cheb[NK];           // 16 KB: 2*cos(2*pi*mu)
    __shared__ bf16_t   Sl[2][BN][LDK];     // 36.9 KB double-buffered S tile [l][k]

    const int tid = threadIdx.x;
    const int bid = blockIdx.x;
    // XCD swizzle: m-tile pinned per XCD pair -> W slice (2MB f32) L2-resident
    const int mt = (bid >> 1) & 3;
    const int nt = ((bid >> 3) << 1) | (bid & 1);
    const int m0 = mt * BM;
    const int n0 = nt * BN;

    // ---- per-block phase tables (once; doubles, ~8 entries/thread) ----
    for (int i = tid; i < NK; i += 512) {
        double mu = (double)Lam[i] * 0.15915494309189535;
        int a = (int)rint(mu * 8192.0);
        double eps = mu - (double)a * (1.0 / 8192.0);
        int e = (int)rint(eps * 536870912.0);
        e = e > 32767 ? 32767 : (e < -32768 ? -32768 : e);
        tbl[i] = ((uint32_t)a << 16) | ((uint32_t)e & 0xffffu);
        double fr = mu - rint(mu);
        cheb[i] = 2.0f * __builtin_amdgcn_cosf((float)fr);
    }

    const int wid  = tid >> 6;
    const int lane = tid & 63;
    const bool producer = (wid < 4);

    // ---- producer geometry: thread owns k-pair x 16 adjacent l ----
    const int skk  = (tid & 31) * 2;        // 32 k-pairs (tid 0..255)
    const int srow = ((tid >> 5) & 7) * 16; // 8 l-groups of 16
    const int sl0  = n0 + srow;
    const float l29 = (float)sl0 * 0x1p-29f;

    auto chain16 = [&](uint32_t pk, float c2, float* c) {
        float ef = (float)(int)(short)(pk & 0xffffu);
        uint32_t a = pk >> 16;
        uint32_t prod = a * (uint32_t)sl0;                    // exact phase mod 2^13
        float f0 = fmaf((float)(prod & 8191u), 0x1p-13f, ef * l29);
        f0 -= rintf(f0);
        float mu = fmaf((float)a, 0x1p-13f, ef * 0x1p-29f);
        float f1 = f0 + mu; f1 -= rintf(f1);
        c[0] = __builtin_amdgcn_cosf(f0);                     // revolutions
        c[1] = __builtin_amdgcn_cosf(f1);
        #pragma unroll
        for (int j = 2; j < 16; ++j) c[j] = fmaf(c2, c[j - 1], -c[j - 2]);
    };

    auto stageS = [&](int buf, int k0) {
        const int k = k0 + skk;
        uint32_t pkA = tbl[k], pkB = tbl[k + 1];
        float cA = cheb[k], cB = cheb[k + 1];
        float ca[16], cb[16];
        chain16(pkA, cA, ca);
        chain16(pkB, cB, cb);
        #pragma unroll
        for (int j = 0; j < 16; ++j)
            *(uint32_t*)&Sl[buf][srow + j][skk] = cvt_pk(ca[j], cb[j]);
    };

    // ---- consumer geometry: 4 waves, each a 64x64 tile (2x2 frags of 32x32) ----
    const int cw  = wid - 4;
    const int wm  = ((cw >> 1) & 1) * 64;
    const int wn  = (cw & 1) * 64;
    const int r31 = lane & 31;
    const int hi8 = (lane >> 5) * 8;
    const float* arow0 = W + (size_t)(m0 + wm + r31) * NK;
    const float* arow1 = W + (size_t)(m0 + wm + 32 + r31) * NK;

    f32x16 acc[2][2];
    #pragma unroll
    for (int i = 0; i < 2; ++i)
        #pragma unroll
        for (int j = 0; j < 2; ++j)
            #pragma unroll
            for (int r = 0; r < 16; ++r)
                acc[i][j][r] = 0.f;

    float4 pfA[2][8], pfB[2][8];            // A prefetch (f32), parity-alternating

    auto loadA = [&](float4 (&pf)[2][8], int it) {
        #pragma unroll
        for (int mi = 0; mi < 2; ++mi) {
            const float4* b = (const float4*)(mi ? arow1 : arow0) + it * 16 + (hi8 >> 2);
            #pragma unroll
            for (int ks = 0; ks < 4; ++ks) {
                pf[mi][ks * 2]     = b[ks * 4];
                pf[mi][ks * 2 + 1] = b[ks * 4 + 1];
            }
        }
    };

    auto consume = [&](int buf, float4 (&pin)[2][8], float4 (&pout)[2][8], int nextIt) {
        bf16x8 af[2][4];
        #pragma unroll
        for (int mi = 0; mi < 2; ++mi)
            #pragma unroll
            for (int ks = 0; ks < 4; ++ks) {
                float4 p0 = pin[mi][ks * 2], p1 = pin[mi][ks * 2 + 1];
                union { uint4 q; bf16x8 v; } w;
                w.q.x = cvt_pk(p0.x, p0.y); w.q.y = cvt_pk(p0.z, p0.w);
                w.q.z = cvt_pk(p1.x, p1.y); w.q.w = cvt_pk(p1.z, p1.w);
                af[mi][ks] = w.v;
            }
        loadA(pout, nextIt > 63 ? 63 : nextIt);   // prefetch; drained by next barrier
        bf16x8 bfr[2][4];
        #pragma unroll
        for (int ni = 0; ni < 2; ++ni)
            #pragma unroll
            for (int ks = 0; ks < 4; ++ks)
                bfr[ni][ks] = *(const bf16x8*)&Sl[buf][wn + ni * 32 + r31][ks * 16 + hi8];
        __builtin_amdgcn_s_setprio(1);
        #pragma unroll
        for (int ks = 0; ks < 4; ++ks)
            #pragma unroll
            for (int mi = 0; mi < 2; ++mi)
                #pragma unroll
                for (int ni = 0; ni < 2; ++ni)
                    acc[mi][ni] = __builtin_amdgcn_mfma_f32_32x32x16_bf16(
                        af[mi][ks], bfr[ni][ks], acc[mi][ni], 0, 0, 0);
        __builtin_amdgcn_s_setprio(0);
    };

    __syncthreads();    // tables ready

    // ---- prologue: producers fill buf0; consumers issue A(it=0) ----
    if (producer) stageS(0, 0);
    else          loadA(pfA, 0);
    __syncthreads();

    // ---- main loop: 64 K-steps, unrolled x2 for compile-time parity ----
    for (int it2 = 0; it2 < 32; ++it2) {
        const int it = it2 * 2;
        if (producer) stageS(1, (it + 1) * BK);            // it even: fill buf1
        else          consume(0, pfA, pfB, it + 1);
        __syncthreads();
        if (producer) { if (it + 1 < 63) stageS(0, (it + 2) * BK); }
        else          consume(1, pfB, pfA, it + 2);
        __syncthreads();
    }

    // ---- epilogue (consumers only): 32x32 C/D layout ----
    if (!producer) {
        #pragma unroll
        for (int mi = 0; mi < 2; ++mi)
            #pragma unroll
            for (int ni = 0; ni < 2; ++ni) {
                const int col = n0 + wn + ni * 32 + r31;
                const int rbase = m0 + wm + mi * 32 + 4 * (lane >> 5);
                #pragma unroll
                for (int rr = 0; rr < 16; ++rr) {
                    const int row = rbase + (rr & 3) + 8 * (rr >> 2);
                    out[(size_t)row * LO + col] = acc[mi][ni][rr];
                }
            }
    }
}

extern "C" void kernel_launch(void* const* d_in, const int* in_sizes, int n_in,
                              void* d_out, int out_size, void* d_ws, size_t ws_size,
                              hipStream_t stream) {
    const float* W = (const float*)d_in[0];
    const float* Lam = (const float*)d_in[1];
    float* out = (float*)d_out;
    dlr_pc<<<dim3(256), dim3(512), 0, stream>>>(W, Lam, out);
}

// Round 7
// 127.333 us; speedup vs baseline: 1.9126x; 1.9126x over previous
//
#include <hip/hip_runtime.h>
#include <hip/hip_bf16.h>
#include <math.h>

// K[c,h,l] = sum_n W[c,h,n] * cos(Lambda[n]*l)
// GEMM (512 x 4096) x (4096 x 8192). Producer/consumer wave specialization:
//   waves 0-3: generate S-tile (Chebyshev chains over l) -> LDS, double-buffered
//   waves 4-7: MFMA; each wave owns 32 rows x 128 cols (NO A duplication),
//              A read global->reg f32 (L2-resident slice), single prefetch buffer.

typedef __bf16 bf16_t;
typedef bf16_t bf16x8 __attribute__((ext_vector_type(8)));
typedef float f32x16 __attribute__((ext_vector_type(16)));

#define NK 4096
#define LO 8192
#define BM 128
#define BN 128
#define BK 64
#define LDK 72   // Sl row stride (bf16): 144B, odd 16B multiple -> conflict-free b128 (HW: 0 conflicts, rounds 3/5)

__device__ __forceinline__ uint32_t cvt_pk(float lo, float hi) {
    uint32_t r;
    asm("v_cvt_pk_bf16_f32 %0, %1, %2" : "=v"(r) : "v"(lo), "v"(hi));
    return r;
}

__global__ __launch_bounds__(512, 2) void dlr_pc2(
    const float* __restrict__ W,
    const float* __restrict__ Lam,
    float* __restrict__ out)
{
    __shared__ uint32_t tbl[NK];            // (a<<16)|(e&0xffff): mu = a/2^13 + e*2^-29
    __shared__ float    cheb[NK];           // 2*cos(2*pi*mu)
    __shared__ bf16_t   Sl[2][BN][LDK];     // double-buffered S tile [l][k]

    const int tid = threadIdx.x;
    const int bid = blockIdx.x;
    // XCD swizzle: m-tile pinned per XCD pair -> 2MB f32 W slice stays L2-resident
    const int mt = (bid >> 1) & 3;
    const int nt = ((bid >> 3) << 1) | (bid & 1);
    const int m0 = mt * BM;
    const int n0 = nt * BN;

    // ---- per-block phase tables (once) ----
    for (int i = tid; i < NK; i += 512) {
        double mu = (double)Lam[i] * 0.15915494309189535;
        int a = (int)rint(mu * 8192.0);
        double eps = mu - (double)a * (1.0 / 8192.0);
        int e = (int)rint(eps * 536870912.0);
        e = e > 32767 ? 32767 : (e < -32768 ? -32768 : e);
        tbl[i] = ((uint32_t)a << 16) | ((uint32_t)e & 0xffffu);
        double fr = mu - rint(mu);
        cheb[i] = 2.0f * __builtin_amdgcn_cosf((float)fr);
    }

    const int wid  = tid >> 6;
    const int lane = tid & 63;
    const bool producer = (wid < 4);

    // ---- producer geometry: thread owns k-pair x 16 adjacent l (tid 0..255) ----
    const int skk  = (tid & 31) * 2;
    const int srow = ((tid >> 5) & 7) * 16;
    const int sl0  = n0 + srow;
    const float l29 = (float)sl0 * 0x1p-29f;

    auto chain16 = [&](uint32_t pk, float c2, float* c) {
        float ef = (float)(int)(short)(pk & 0xffffu);
        uint32_t a = pk >> 16;
        uint32_t prod = a * (uint32_t)sl0;                    // exact phase mod 2^13
        float f0 = fmaf((float)(prod & 8191u), 0x1p-13f, ef * l29);
        f0 -= rintf(f0);
        float mu = fmaf((float)a, 0x1p-13f, ef * 0x1p-29f);
        float f1 = f0 + mu; f1 -= rintf(f1);
        c[0] = __builtin_amdgcn_cosf(f0);                     // revolutions
        c[1] = __builtin_amdgcn_cosf(f1);
        #pragma unroll
        for (int j = 2; j < 16; ++j) c[j] = fmaf(c2, c[j - 1], -c[j - 2]);
    };

    auto stageS = [&](int buf, int k0) {
        const int k = k0 + skk;
        uint32_t pkA = tbl[k], pkB = tbl[k + 1];
        float cA = cheb[k], cB = cheb[k + 1];
        float ca[16], cb[16];
        chain16(pkA, cA, ca);
        chain16(pkB, cB, cb);
        #pragma unroll
        for (int j = 0; j < 16; ++j)
            *(uint32_t*)&Sl[buf][srow + j][skk] = cvt_pk(ca[j], cb[j]);
    };

    // ---- consumer geometry: wave cw owns rows [m0+cw*32, +32), all BN cols ----
    const int cw  = wid - 4;
    const int r31 = lane & 31;
    const int hi8 = (lane >> 5) * 8;
    const float* arow = W + (size_t)(m0 + cw * 32 + r31) * NK + hi8;

    f32x16 acc[4];
    #pragma unroll
    for (int i = 0; i < 4; ++i)
        #pragma unroll
        for (int r = 0; r < 16; ++r)
            acc[i][r] = 0.f;

    float4 pf[8];                            // single A prefetch buffer (32 VGPR)
    auto loadA = [&](int it) {
        const float4* b = (const float4*)arow + it * 16;   // hi8 is 0/32B -> 16B aligned
        #pragma unroll
        for (int ks = 0; ks < 4; ++ks) {
            pf[ks * 2]     = b[ks * 4];
            pf[ks * 2 + 1] = b[ks * 4 + 1];
        }
    };

    auto consume = [&](int buf, int nextIt) {
        bf16x8 af[4];
        #pragma unroll
        for (int ks = 0; ks < 4; ++ks) {
            float4 p0 = pf[ks * 2], p1 = pf[ks * 2 + 1];
            union { uint4 q; bf16x8 v; } w;
            w.q.x = cvt_pk(p0.x, p0.y); w.q.y = cvt_pk(p0.z, p0.w);
            w.q.z = cvt_pk(p1.x, p1.y); w.q.w = cvt_pk(p1.z, p1.w);
            af[ks] = w.v;
        }
        loadA(nextIt);                       // issue next-iter A; lands by next use
        __builtin_amdgcn_s_setprio(1);
        #pragma unroll
        for (int ks = 0; ks < 4; ++ks) {
            #pragma unroll
            for (int ni = 0; ni < 4; ++ni) {
                bf16x8 bv = *(const bf16x8*)&Sl[buf][ni * 32 + r31][ks * 16 + hi8];
                acc[ni] = __builtin_amdgcn_mfma_f32_32x32x16_bf16(
                    af[ks], bv, acc[ni], 0, 0, 0);
            }
        }
        __builtin_amdgcn_s_setprio(0);
    };

    __syncthreads();    // tables ready

    // ---- prologue ----
    if (producer) stageS(0, 0);
    else          loadA(0);
    __syncthreads();

    // ---- main loop: 64 K-steps, one barrier each ----
    for (int it = 0; it < 64; ++it) {
        if (producer) {
            if (it < 63) stageS((it + 1) & 1, (it + 1) * BK);
        } else {
            consume(it & 1, it + 1 > 63 ? 63 : it + 1);
        }
        __syncthreads();
    }

    // ---- epilogue (consumers): 32x32 C/D layout col=lane&31, row=(reg&3)+8*(reg>>2)+4*(lane>>5) ----
    if (!producer) {
        const int rbase = m0 + cw * 32 + 4 * (lane >> 5);
        #pragma unroll
        for (int ni = 0; ni < 4; ++ni) {
            const int col = n0 + ni * 32 + r31;
            #pragma unroll
            for (int rr = 0; rr < 16; ++rr) {
                const int row = rbase + (rr & 3) + 8 * (rr >> 2);
                out[(size_t)row * LO + col] = acc[ni][rr];
            }
        }
    }
}

extern "C" void kernel_launch(void* const* d_in, const int* in_sizes, int n_in,
                              void* d_out, int out_size, void* d_ws, size_t ws_size,
                              hipStream_t stream) {
    const float* W = (const float*)d_in[0];
    const float* Lam = (const float*)d_in[1];
    float* out = (float*)d_out;
    dlr_pc2<<<dim3(256), dim3(512), 0, stream>>>(W, Lam, out);
}